// Round 1
// baseline (606.140 us; speedup 1.0000x reference)
//
#include <hip/hip_runtime.h>

// Per row (64 floats of exact {0,1}):
//   e     = bits x[1..11], x[1] = bit10 (MSB) ... x[11] = bit0
//   d     = (e - 1023) & 2047
//   mant6 = bits x[12..17], x[12] = bit5 (MSB) ... x[17] = bit0
//   low6  = (d <= 5) ? (((0x40 | mant6) << d) >> 6) & 63 : 0
//   out[j] = bit (5-j) of low6   (MSB first), j = 0..5
__global__ __launch_bounds__(256) void extract_low6_kernel(
    const float* __restrict__ x, float* __restrict__ out, int nrows) {
    int r = blockIdx.x * blockDim.x + threadIdx.x;
    if (r >= nrows) return;

    const float* row = x + (size_t)r * 64;
    // Only bytes [0,72) of the 256B row are needed: cols 0..17.
    float4 f0 = *(const float4*)(row);       // cols 0..3   (col 0 = sign, unused)
    float4 f1 = *(const float4*)(row + 4);   // cols 4..7
    float4 f2 = *(const float4*)(row + 8);   // cols 8..11
    float4 f3 = *(const float4*)(row + 12);  // cols 12..15
    float2 f4 = *(const float2*)(row + 16);  // cols 16..17

    int e = 0;
    e |= (int)(f0.y != 0.f) << 10;  // x1
    e |= (int)(f0.z != 0.f) << 9;   // x2
    e |= (int)(f0.w != 0.f) << 8;   // x3
    e |= (int)(f1.x != 0.f) << 7;   // x4
    e |= (int)(f1.y != 0.f) << 6;   // x5
    e |= (int)(f1.z != 0.f) << 5;   // x6
    e |= (int)(f1.w != 0.f) << 4;   // x7
    e |= (int)(f2.x != 0.f) << 3;   // x8
    e |= (int)(f2.y != 0.f) << 2;   // x9
    e |= (int)(f2.z != 0.f) << 1;   // x10
    e |= (int)(f2.w != 0.f);        // x11

    int mant = 0;
    mant |= (int)(f3.x != 0.f) << 5;  // x12 (mantissa MSB)
    mant |= (int)(f3.y != 0.f) << 4;  // x13
    mant |= (int)(f3.z != 0.f) << 3;  // x14
    mant |= (int)(f3.w != 0.f) << 2;  // x15
    mant |= (int)(f4.x != 0.f) << 1;  // x16
    mant |= (int)(f4.y != 0.f);       // x17

    unsigned d = (unsigned)(e - 1023) & 2047u;
    int low6 = (d <= 5u) ? (((0x40 | mant) << d) >> 6) & 63 : 0;

    // out row = 6 floats, MSB first. 24B per row, 8B-aligned -> three float2 stores.
    float2* o = (float2*)(out + (size_t)r * 6);
    o[0] = make_float2((float)((low6 >> 5) & 1), (float)((low6 >> 4) & 1));
    o[1] = make_float2((float)((low6 >> 3) & 1), (float)((low6 >> 2) & 1));
    o[2] = make_float2((float)((low6 >> 1) & 1), (float)(low6 & 1));
}

extern "C" void kernel_launch(void* const* d_in, const int* in_sizes, int n_in,
                              void* d_out, int out_size, void* d_ws, size_t ws_size,
                              hipStream_t stream) {
    const float* x = (const float*)d_in[0];
    float* out = (float*)d_out;
    int nrows = in_sizes[0] / 64;  // 2,000,000
    int block = 256;
    int grid = (nrows + block - 1) / block;
    extract_low6_kernel<<<grid, block, 0, stream>>>(x, out, nrows);
}